// Round 7
// baseline (1090.719 us; speedup 1.0000x reference)
//
#include <hip/hip_runtime.h>

#define T_DIM 512
#define B_DIM 512
#define OBS_DIM 128
#define H_DIM 128
#define A_DIM 18
#define G3 384
#define LDSS 136        // LDS row stride in halfs (128 + 8 pad, 16B-aligned rows)
#define NPROD 224       // producer blocks (blockIdx 32..255)
#define NUNITS 8192     // 512 t x 16 units (M=32 rows each)

// exp-argument scales folded into weights/biases/stored gi:
//  r,z gates: arg' = -log2e * arg   (sigmoid(x) = 1/(1+2^(arg')))
//  n gate:    arg' = 2*log2e * arg  (tanh(x) = (2^(arg')-1)/(2^(arg')+1))
#define SC_R (-1.44269504088896f)
#define SC_N (2.88539008177793f)

typedef _Float16 v8h __attribute__((ext_vector_type(8)));
typedef _Float16 v4h __attribute__((ext_vector_type(4)));
typedef float v4f __attribute__((ext_vector_type(4)));

#define EXP2F(x) __builtin_amdgcn_exp2f(x)
#define RCPF(x)  __builtin_amdgcn_rcpf(x)

// LDS-only barrier: drains lgkmcnt but leaves vmcnt in flight.
#define BAR() asm volatile("s_waitcnt lgkmcnt(0)\n\ts_barrier" ::: "memory")

// flags layout (int array in d_out q-tail, zeroed by memset each call):
//  [0..511]  per-t unit counters; ==16 means gi row-block t fully published
//  [512]     consumer-done counter (==32)
//  [513]     producer-ack counter (==224)

__device__ __forceinline__ int loadf(const int* f) {
    return __hip_atomic_load(f, __ATOMIC_RELAXED, __HIP_MEMORY_SCOPE_AGENT);
}
__device__ __forceinline__ void pollf16(const int* f) {
    while (loadf(f) != 16) __builtin_amdgcn_s_sleep(8);
    asm volatile("" ::: "memory");
}
// L2-bypassing 16B load as 4 agent-scope dwords (for q-phase ys reads)
__device__ __forceinline__ v8h load16_coh(const _Float16* p) {
    const int* q = (const int*)p;
    union { int4 i; v8h h; } u;
    u.i.x = loadf(q + 0); u.i.y = loadf(q + 1);
    u.i.z = loadf(q + 2); u.i.w = loadf(q + 3);
    return u.h;
}

__global__ __launch_bounds__(512) void fused(
    const float* __restrict__ hidden,
    const unsigned char* __restrict__ dones_raw,
    const float* __restrict__ obs,
    const float* __restrict__ W_emb,
    const float* __restrict__ b_emb,
    const float* __restrict__ Wi,
    const float* __restrict__ bi,
    const float* __restrict__ Wh,
    const float* __restrict__ bhn,
    const float* __restrict__ W_out,
    const float* __restrict__ b_out,
    _Float16* __restrict__ gRZ,
    _Float16* __restrict__ gN,
    int* __restrict__ flags,
    float* __restrict__ out)
{
    __shared__ __align__(16) char smem[17472];
    const int tid  = threadIdx.x;
    const int lane = tid & 63;
    const int n16  = lane & 15;
    const int quad = lane >> 4;
    float* qout = out + (size_t)B_DIM * H_DIM;

    if (blockIdx.x >= 32) {
        // ===================== PRODUCER =====================
        _Float16* obs_lds = (_Float16*)smem;                 // 32*LDSS halfs
        _Float16* emb_lds = (_Float16*)(smem + 8704);        // 32*LDSS halfs
        const int cg = tid >> 6;   // wave = col-group
        const int p  = blockIdx.x - 32;

        // A-frags: lane holds A[m=n16][k=kt*32+quad*8+j]; gate scales folded in.
        v8h fe[4];
        v8h fi[3][4];
#pragma unroll
        for (int kt = 0; kt < 4; ++kt)
#pragma unroll
            for (int j = 0; j < 8; ++j) {
                const int k = kt * 32 + quad * 8 + j;
                fe[kt][j] = (_Float16)W_emb[k * H_DIM + cg * 16 + n16];
            }
#pragma unroll
        for (int g = 0; g < 3; ++g) {
            const float sc = (g == 2) ? SC_N : SC_R;
#pragma unroll
            for (int kt = 0; kt < 4; ++kt)
#pragma unroll
                for (int j = 0; j < 8; ++j) {
                    const int k = kt * 32 + quad * 8 + j;
                    fi[g][kt][j] = (_Float16)(Wi[k * G3 + g * H_DIM + cg * 16 + n16] * sc);
                }
        }
        float bemb[4], bir[4], biz[4], bin_[4];
#pragma unroll
        for (int r = 0; r < 4; ++r) {
            const int col = cg * 16 + quad * 4 + r;
            bemb[r] = b_emb[col];
            bir[r]  = bi[col] * SC_R;
            biz[r]  = bi[H_DIM + col] * SC_R;
            bin_[r] = bi[2 * H_DIM + col] * SC_N;
        }

        const int srow = tid >> 4;          // 0..31
        const int sk   = (tid & 15) * 8;    // 0..120

        // stage first unit's obs
        int u = p;
        {
            const int row0 = (u >> 4) * B_DIM + (u & 15) * 32;
            const float* op = obs + (size_t)(row0 + srow) * OBS_DIM + sk;
            const float4 a = *(const float4*)op;
            const float4 b = *(const float4*)(op + 4);
            v4h pa = { (_Float16)a.x, (_Float16)a.y, (_Float16)a.z, (_Float16)a.w };
            v4h pb = { (_Float16)b.x, (_Float16)b.y, (_Float16)b.z, (_Float16)b.w };
            *(v4h*)&obs_lds[srow * LDSS + sk]     = pa;
            *(v4h*)&obs_lds[srow * LDSS + sk + 4] = pb;
        }
        __syncthreads();

        while (u < NUNITS) {
            const int t    = u >> 4;
            const int row0 = t * B_DIM + (u & 15) * 32;
            const int un   = u + NPROD;
            const int rn   = (un < NUNITS) ? (un >> 4) * B_DIM + (un & 15) * 32 : row0;
            const float* opn = obs + (size_t)(rn + srow) * OBS_DIM + sk;
            const float4 na = *(const float4*)opn;
            const float4 nb = *(const float4*)(opn + 4);

            // phase A: emb tiles (2 row-tiles x 16 cols)
            v8h bo[2][4];
#pragma unroll
            for (int rt = 0; rt < 2; ++rt)
#pragma unroll
                for (int kt = 0; kt < 4; ++kt)
                    bo[rt][kt] = *(const v8h*)&obs_lds[(rt * 16 + n16) * LDSS + kt * 32 + quad * 8];
            v4f ea[2] = {{0.f,0.f,0.f,0.f},{0.f,0.f,0.f,0.f}};
#pragma unroll
            for (int rt = 0; rt < 2; ++rt)
#pragma unroll
                for (int kt = 0; kt < 4; ++kt)
                    ea[rt] = __builtin_amdgcn_mfma_f32_16x16x32_f16(fe[kt], bo[rt][kt], ea[rt], 0, 0, 0);
#pragma unroll
            for (int rt = 0; rt < 2; ++rt) {
                v4h e;
#pragma unroll
                for (int r = 0; r < 4; ++r) e[r] = (_Float16)fmaxf(ea[rt][r] + bemb[r], 0.f);
                *(v4h*)&emb_lds[(rt * 16 + n16) * LDSS + cg * 16 + quad * 4] = e;
            }
            BAR();
            // phase B: gi tiles
            v8h be[2][4];
#pragma unroll
            for (int rt = 0; rt < 2; ++rt)
#pragma unroll
                for (int kt = 0; kt < 4; ++kt)
                    be[rt][kt] = *(const v8h*)&emb_lds[(rt * 16 + n16) * LDSS + kt * 32 + quad * 8];
            v4f ar[2] = {{0.f,0.f,0.f,0.f},{0.f,0.f,0.f,0.f}};
            v4f az[2] = {{0.f,0.f,0.f,0.f},{0.f,0.f,0.f,0.f}};
            v4f an[2] = {{0.f,0.f,0.f,0.f},{0.f,0.f,0.f,0.f}};
#pragma unroll
            for (int rt = 0; rt < 2; ++rt)
#pragma unroll
                for (int kt = 0; kt < 4; ++kt) {
                    ar[rt] = __builtin_amdgcn_mfma_f32_16x16x32_f16(fi[0][kt], be[rt][kt], ar[rt], 0, 0, 0);
                    az[rt] = __builtin_amdgcn_mfma_f32_16x16x32_f16(fi[1][kt], be[rt][kt], az[rt], 0, 0, 0);
                    an[rt] = __builtin_amdgcn_mfma_f32_16x16x32_f16(fi[2][kt], be[rt][kt], an[rt], 0, 0, 0);
                }
#pragma unroll
            for (int rt = 0; rt < 2; ++rt) {
                const int R = row0 + rt * 16 + n16;
                v8h rz;
#pragma unroll
                for (int r = 0; r < 4; ++r) {
                    rz[r]     = (_Float16)(ar[rt][r] + bir[r]);
                    rz[4 + r] = (_Float16)(az[rt][r] + biz[r]);
                }
                *(v8h*)&gRZ[(size_t)R * 256 + cg * 32 + quad * 8] = rz;
                v4h nn;
#pragma unroll
                for (int r = 0; r < 4; ++r) nn[r] = (_Float16)(an[rt][r] + bin_[r]);
                *(v4h*)&gN[(size_t)R * 128 + cg * 16 + quad * 4] = nn;
            }
            // stage next unit's obs (obs_lds reads all ended before BAR)
            {
                v4h pa = { (_Float16)na.x, (_Float16)na.y, (_Float16)na.z, (_Float16)na.w };
                v4h pb = { (_Float16)nb.x, (_Float16)nb.y, (_Float16)nb.z, (_Float16)nb.w };
                *(v4h*)&obs_lds[srow * LDSS + sk]     = pa;
                *(v4h*)&obs_lds[srow * LDSS + sk + 4] = pb;
            }
            __syncthreads();          // drain gi stores (all threads) + LDS fence
            if (tid == 0) {
                __threadfence();      // wbl2: push gi to LLC; producer L2 now clean
                atomicAdd(&flags[t], 1);
            }
            u = un;
        }

        // ---------- q phase: q = ys @ W_out + b_out for t = p, p+224, p+448 ----
        v8h fo[2][4];
#pragma unroll
        for (int ct = 0; ct < 2; ++ct)
#pragma unroll
            for (int kt = 0; kt < 4; ++kt)
#pragma unroll
                for (int j = 0; j < 8; ++j) {
                    const int k = kt * 32 + quad * 8 + j;
                    const int col = ct * 16 + n16;
                    fo[ct][kt][j] = (col < A_DIM) ? (_Float16)W_out[k * A_DIM + col] : (_Float16)0.f;
                }
        float bq0[4], bq1[4];
#pragma unroll
        for (int r = 0; r < 4; ++r) {
            const int c0 = quad * 4 + r;
            const int c1 = 16 + quad * 4 + r;
            bq0[r] = b_out[c0];
            bq1[r] = (c1 < A_DIM) ? b_out[c1] : 0.f;
        }
        // double gate: wait all 32 consumers done, then all 224 producers acked.
        // After both, nobody reads flags[512]/[513] again -> q may clobber tail.
        if (tid == 0) {
            while (loadf(&flags[512]) != 32) __builtin_amdgcn_s_sleep(64);
            atomicAdd(&flags[513], 1);
            while (loadf(&flags[513]) != NPROD) __builtin_amdgcn_s_sleep(64);
        }
        __syncthreads();

        for (int ci = 0; ci < 3; ++ci) {
            const int t = p + ci * NPROD;
            if (t >= T_DIM) break;
#pragma unroll
            for (int s = 0; s < 4; ++s) {
                const int row = t * B_DIM + cg * 64 + s * 16 + n16;
                v8h by[4];
#pragma unroll
                for (int kt = 0; kt < 4; ++kt)
                    by[kt] = load16_coh(gN + (size_t)row * 128 + kt * 32 + quad * 8);
                v4f q0 = {0.f,0.f,0.f,0.f}, q1 = {0.f,0.f,0.f,0.f};
#pragma unroll
                for (int kt = 0; kt < 4; ++kt) {
                    q0 = __builtin_amdgcn_mfma_f32_16x16x32_f16(fo[0][kt], by[kt], q0, 0, 0, 0);
                    q1 = __builtin_amdgcn_mfma_f32_16x16x32_f16(fo[1][kt], by[kt], q1, 0, 0, 0);
                }
                float* qp = qout + (size_t)row * A_DIM;
#pragma unroll
                for (int r = 0; r < 4; ++r) qp[quad * 4 + r] = q0[r] + bq0[r];
                if (quad == 0) {
#pragma unroll
                    for (int r = 0; r < 2; ++r) qp[16 + r] = q1[r] + bq1[r];
                }
            }
        }
        return;
    }

    // ===================== CONSUMER (GRU recurrence) =====================
    _Float16 (*h_lds)[16 * LDSS] = (_Float16(*)[16 * LDSS])smem;   // 2 x 4352 B
    unsigned char* d_lds = (unsigned char*)(smem + 8704);          // 513*16 B
    int* bm_p = (int*)(smem + 16912);
    const int w   = tid >> 6;
    const int c16 = w * 16 + quad * 4;
    const int B0  = blockIdx.x * 16;

    if (tid == 0) *bm_p = 0;
    __syncthreads();
    {   // detect dones element width: byte==1 at non-4-aligned offset => 1-byte bools
        int hit = 0;
        for (int i = tid; i < 4096; i += 512)
            if ((i & 3) != 0 && dones_raw[i] == 1) hit = 1;
        if (hit) *bm_p = 1;
    }
    __syncthreads();
    const bool bm = (*bm_p != 0);

    // stage this block's dones slice: d_lds[t*16 + b]; row T zeroed
    {
        if (bm) {
            const int4 v = *(const int4*)(dones_raw + (size_t)tid * B_DIM + B0);
            *(int4*)&d_lds[tid * 16] = v;
        } else {
            const int* di = (const int*)dones_raw;
            const int* pp = di + (size_t)tid * B_DIM + B0;
            int4 wv; unsigned char* wb = (unsigned char*)&wv;
#pragma unroll
            for (int j = 0; j < 16; ++j) wb[j] = (unsigned char)(pp[j] != 0);
            *(int4*)&d_lds[tid * 16] = wv;
        }
        if (tid == 0) { int4 z = {0,0,0,0}; *(int4*)&d_lds[T_DIM * 16] = z; }
    }

    // Wh^T A-frags, gate scales folded in
    v8h fh[3][4];
#pragma unroll
    for (int g = 0; g < 3; ++g) {
        const float sc = (g == 2) ? SC_N : SC_R;
#pragma unroll
        for (int kt = 0; kt < 4; ++kt)
#pragma unroll
            for (int j = 0; j < 8; ++j) {
                const int k = kt * 32 + quad * 8 + j;
                fh[g][kt][j] = (_Float16)(Wh[k * G3 + g * H_DIM + w * 16 + n16] * sc);
            }
    }
    float bhnr[4];
#pragma unroll
    for (int r = 0; r < 4; ++r) bhnr[r] = bhn[c16 + r] * SC_N;

    __syncthreads();   // d_lds visible

    // init carry, pre-masked with done[0]
    const bool d0 = d_lds[n16] != 0;
    float hu[4];
#pragma unroll
    for (int r = 0; r < 4; ++r) {
        const float hv = hidden[(size_t)(B0 + n16) * H_DIM + c16 + r];
        hu[r] = d0 ? 0.f : hv;
    }
    {
        v4h hw = { (_Float16)hu[0], (_Float16)hu[1], (_Float16)hu[2], (_Float16)hu[3] };
        *(v4h*)&h_lds[0][n16 * LDSS + c16] = hw;
    }

    const _Float16* rzp = gRZ + (size_t)(B0 + n16) * 256 + w * 32 + quad * 8;
    _Float16*       np  = gN  + (size_t)(B0 + n16) * 128 + c16;
    const size_t RZT = (size_t)B_DIM * 256;
    const size_t NT  = (size_t)B_DIM * 128;

    // wait for t=0..7, then start the pipelined flag batches
    for (int i = 0; i < 8; ++i) pollf16(&flags[i]);
    int fb = 8;
    int4 fpend; fpend.x = loadf(&flags[8]); fpend.y = loadf(&flags[9]);
    fpend.z = loadf(&flags[10]); fpend.w = loadf(&flags[11]);

    // preload t=0,1
    v8h s8_0 = *(const v8h*)(rzp);
    v4h s4_0 = *(const v4h*)(np);
    v8h s8_1 = *(const v8h*)(rzp + RZT);
    v4h s4_1 = *(const v4h*)(np + NT);
    __syncthreads();   // h_lds[0] visible

    auto STEP = [&](int t, v8h& s8, v4h& s4, const _Float16* hin, _Float16* hout)
        __attribute__((always_inline)) -> void {
        const int tp = (t + 2 < T_DIM) ? t + 2 : T_DIM - 1;
        const v8h gC8 = *(const v8h*)(rzp + (size_t)tp * RZT);
        const v4h gC4 = *(const v4h*)(np + (size_t)tp * NT);
        const unsigned char dnx = d_lds[(t + 1) * 16 + n16];

        v8h bh[4];
#pragma unroll
        for (int kt = 0; kt < 4; ++kt)
            bh[kt] = *(const v8h*)&hin[n16 * LDSS + kt * 32 + quad * 8];

        v4f ga0 = {0.f,0.f,0.f,0.f}, ga1 = {0.f,0.f,0.f,0.f}, ga2 = {0.f,0.f,0.f,0.f};
#pragma unroll
        for (int kt = 0; kt < 4; ++kt) {
            ga0 = __builtin_amdgcn_mfma_f32_16x16x32_f16(fh[0][kt], bh[kt], ga0, 0, 0, 0);
            ga1 = __builtin_amdgcn_mfma_f32_16x16x32_f16(fh[1][kt], bh[kt], ga1, 0, 0, 0);
            ga2 = __builtin_amdgcn_mfma_f32_16x16x32_f16(fh[2][kt], bh[kt], ga2, 0, 0, 0);
        }

        // fused gates: h = [ez*(en-1) + hu*(en+1)] / [(en+1)*(1+ez)]
        float hn[4];
#pragma unroll
        for (int r = 0; r < 4; ++r) {
            const float er = EXP2F((float)s8[r] + ga0[r]);
            const float rg = RCPF(1.f + er);
            const float sn = fmaf(rg, ga2[r] + bhnr[r], (float)s4[r]);
            const float en = EXP2F(sn);
            const float ez = EXP2F((float)s8[4 + r] + ga1[r]);
            const float enp = en + 1.f;
            const float num = fmaf(hu[r], enp, (en - 1.f) * ez);
            const float den = enp * (1.f + ez);
            hn[r] = num * RCPF(den);
        }

        // ys[t] (unmasked) -> gN row t (consumed >= 2 steps ago)
        v4h yv = { (_Float16)hn[0], (_Float16)hn[1], (_Float16)hn[2], (_Float16)hn[3] };
        *(v4h*)(np + (size_t)t * NT) = yv;

        // mask with done[t+1] at write
        const bool dn = dnx != 0;
        v4h hz = { (_Float16)0.f, (_Float16)0.f, (_Float16)0.f, (_Float16)0.f };
        v4h hv = dn ? hz : yv;
#pragma unroll
        for (int r = 0; r < 4; ++r) hu[r] = dn ? 0.f : hn[r];
        *(v4h*)&hout[n16 * LDSS + c16] = hv;

        s8 = gC8; s4 = gC4;
        BAR();
    };

    for (int t = 0; t < T_DIM; t += 2) {
        if ((t & 3) == 0) {
            if (t >= 4) {
                // verify batch loaded 4 steps ago (covers flags[fb..fb+3]);
                // the loads are old -> waitcnt keeps younger gi prefetches in flight
                if (fpend.x != 16) pollf16(&flags[fb]);
                if (fpend.y != 16) pollf16(&flags[fb + 1]);
                if (fpend.z != 16) pollf16(&flags[fb + 2]);
                if (fpend.w != 16) pollf16(&flags[fb + 3]);
            }
            fb = (t + 8 <= 508) ? t + 8 : 508;
            fpend.x = loadf(&flags[fb]);     fpend.y = loadf(&flags[fb + 1]);
            fpend.z = loadf(&flags[fb + 2]); fpend.w = loadf(&flags[fb + 3]);
        }
        STEP(t,     s8_0, s4_0, h_lds[0], h_lds[1]);
        STEP(t + 1, s8_1, s4_1, h_lds[1], h_lds[0]);
    }

    // publish: all ys stores drained block-wide, L2 written back, then count.
    __syncthreads();
    if (tid == 0) { __threadfence(); atomicAdd(&flags[512], 1); }

    // h_final (hu after t=511 is unmasked: d_lds row 512 zeroed)
#pragma unroll
    for (int r = 0; r < 4; ++r)
        out[(size_t)(B0 + n16) * H_DIM + c16 + r] = hu[r];
}

extern "C" void kernel_launch(void* const* d_in, const int* in_sizes, int n_in,
                              void* d_out, int out_size, void* d_ws, size_t ws_size,
                              hipStream_t stream) {
    const float* hidden = (const float*)d_in[0];
    const float* obs    = (const float*)d_in[1];
    const unsigned char* dones = (const unsigned char*)d_in[2];
    const float* W_emb  = (const float*)d_in[3];
    const float* b_emb  = (const float*)d_in[4];
    const float* Wi     = (const float*)d_in[5];
    const float* bi     = (const float*)d_in[6];
    const float* Wh     = (const float*)d_in[7];
    const float* bhn    = (const float*)d_in[8];
    const float* W_out  = (const float*)d_in[9];
    const float* b_out  = (const float*)d_in[10];
    float* out = (float*)d_out;

    _Float16* gRZ = (_Float16*)d_ws;                              // [T*B][256] f16 = 128 MiB
    _Float16* gN  = gRZ + (size_t)T_DIM * B_DIM * 256;            // [T*B][128] f16 =  64 MiB

    // flags: last 514 ints of d_out's q region. Zeroed here each call; those
    // q elements are rewritten with real values by the (double-gated) q phase.
    int* flags = (int*)(out + (size_t)out_size) - 514;
    hipMemsetAsync(flags, 0, 514 * sizeof(int), stream);

    hipLaunchKernelGGL(fused, dim3(256), dim3(512), 0, stream,
                       hidden, dones, obs, W_emb, b_emb, Wi, bi, Wh, bhn,
                       W_out, b_out, gRZ, gN, flags, out);
}

// Round 8
// 715.847 us; speedup vs baseline: 1.5237x; 1.5237x over previous
//
#include <hip/hip_runtime.h>

#define T_DIM 512
#define B_DIM 512
#define OBS_DIM 128
#define H_DIM 128
#define A_DIM 18
#define G3 384
#define LDSS 136        // LDS row stride in halfs (128 + 8 pad, 16B-aligned rows)

// exp-argument scales folded into weights/biases/stored gi:
//  r,z gates: arg' = -log2e * arg   (sigmoid(x) = 1/(1+2^(arg')))
//  n gate:    arg' = 2*log2e * arg  (tanh(x) = (2^(arg')-1)/(2^(arg')+1))
#define SC_R (-1.44269504088896f)
#define SC_N (2.88539008177793f)

typedef _Float16 v8h __attribute__((ext_vector_type(8)));
typedef _Float16 v4h __attribute__((ext_vector_type(4)));
typedef float v4f __attribute__((ext_vector_type(4)));

#define EXP2F(x) __builtin_amdgcn_exp2f(x)
#define RCPF(x)  __builtin_amdgcn_rcpf(x)

// LDS-only barrier: drains lgkmcnt but leaves vmcnt in flight.
#define BAR() asm volatile("s_waitcnt lgkmcnt(0)\n\ts_barrier" ::: "memory")

// ---------------------------------------------------------------------------
// K1: gi = relu(obs @ W_emb + b_emb) @ Wi + bi, stored f16 PRE-SCALED.
// M=64 tile: 64 MFMA per barrier-pair (2.7x the old MFMA:barrier ratio).
// 256 blocks x 16 iters. 8 waves = 8 col-groups of 16.
//   gRZ[row*256 + cg*32 + quad*8 + {0..3: SC_R*r, 4..7: SC_R*z}]
//   gN [row*128 + col] = SC_N * n
// ---------------------------------------------------------------------------
__global__ __launch_bounds__(512) void k1_embed_gi(
    const float* __restrict__ obs,
    const float* __restrict__ W_emb,
    const float* __restrict__ b_emb,
    const float* __restrict__ Wi,
    const float* __restrict__ bi,
    _Float16* __restrict__ gRZ,
    _Float16* __restrict__ gN)
{
    __shared__ __align__(16) _Float16 obs_lds[64 * LDSS];   // 17408 B
    __shared__ __align__(16) _Float16 emb_lds[64 * LDSS];   // 17408 B
    const int tid  = threadIdx.x;
    const int cg   = tid >> 6;     // wave = col-group
    const int lane = tid & 63;
    const int n16  = lane & 15;
    const int quad = lane >> 4;

    // A-frags: lane holds A[m=n16][k=kt*32+quad*8+j]; gate scales folded in.
    v8h fe[4];
    v8h fi[3][4];
#pragma unroll
    for (int kt = 0; kt < 4; ++kt)
#pragma unroll
        for (int j = 0; j < 8; ++j) {
            const int k = kt * 32 + quad * 8 + j;
            fe[kt][j] = (_Float16)W_emb[k * H_DIM + cg * 16 + n16];
        }
#pragma unroll
    for (int g = 0; g < 3; ++g) {
        const float sc = (g == 2) ? SC_N : SC_R;
#pragma unroll
        for (int kt = 0; kt < 4; ++kt)
#pragma unroll
            for (int j = 0; j < 8; ++j) {
                const int k = kt * 32 + quad * 8 + j;
                fi[g][kt][j] = (_Float16)(Wi[k * G3 + g * H_DIM + cg * 16 + n16] * sc);
            }
    }
    float bemb[4], bir[4], biz[4], bin_[4];
#pragma unroll
    for (int r = 0; r < 4; ++r) {
        const int col = cg * 16 + quad * 4 + r;
        bemb[r] = b_emb[col];
        bir[r]  = bi[col] * SC_R;
        biz[r]  = bi[H_DIM + col] * SC_R;
        bin_[r] = bi[2 * H_DIM + col] * SC_N;
    }

    const int srow = tid >> 3;          // 0..63
    const int sk   = (tid & 7) * 16;    // 0..112 (16 floats per thread)
    const int base = blockIdx.x * 16;   // 16 tiles of 64 rows

    // stage iter 0's obs
    {
        const float* op = obs + (size_t)(base * 64 + srow) * OBS_DIM + sk;
#pragma unroll
        for (int q = 0; q < 4; ++q) {
            const float4 a = *(const float4*)(op + q * 4);
            v4h pa = { (_Float16)a.x, (_Float16)a.y, (_Float16)a.z, (_Float16)a.w };
            *(v4h*)&obs_lds[srow * LDSS + sk + q * 4] = pa;
        }
    }
    __syncthreads();

    for (int i = 0; i < 16; ++i) {
        const int row0 = (base + i) * 64;
        const int ni = (i + 1 < 16) ? i + 1 : i;
        const float* opn = obs + (size_t)((base + ni) * 64 + srow) * OBS_DIM + sk;
        float4 nv[4];
#pragma unroll
        for (int q = 0; q < 4; ++q) nv[q] = *(const float4*)(opn + q * 4);

        // phase A: emb, 4 row-tiles x 16 cols per wave
#pragma unroll
        for (int rt = 0; rt < 4; ++rt) {
            v8h bo[4];
#pragma unroll
            for (int kt = 0; kt < 4; ++kt)
                bo[kt] = *(const v8h*)&obs_lds[(rt * 16 + n16) * LDSS + kt * 32 + quad * 8];
            v4f ea = {0.f, 0.f, 0.f, 0.f};
#pragma unroll
            for (int kt = 0; kt < 4; ++kt)
                ea = __builtin_amdgcn_mfma_f32_16x16x32_f16(fe[kt], bo[kt], ea, 0, 0, 0);
            v4h e;
#pragma unroll
            for (int r = 0; r < 4; ++r) e[r] = (_Float16)fmaxf(ea[r] + bemb[r], 0.f);
            *(v4h*)&emb_lds[(rt * 16 + n16) * LDSS + cg * 16 + quad * 4] = e;
        }
        BAR();
        // phase B: gi, 4 row-tiles x 3 gates x 16 cols per wave
#pragma unroll
        for (int rt = 0; rt < 4; ++rt) {
            v8h be[4];
#pragma unroll
            for (int kt = 0; kt < 4; ++kt)
                be[kt] = *(const v8h*)&emb_lds[(rt * 16 + n16) * LDSS + kt * 32 + quad * 8];
            v4f ar = {0.f,0.f,0.f,0.f}, az = {0.f,0.f,0.f,0.f}, an = {0.f,0.f,0.f,0.f};
#pragma unroll
            for (int kt = 0; kt < 4; ++kt) {
                ar = __builtin_amdgcn_mfma_f32_16x16x32_f16(fi[0][kt], be[kt], ar, 0, 0, 0);
                az = __builtin_amdgcn_mfma_f32_16x16x32_f16(fi[1][kt], be[kt], az, 0, 0, 0);
                an = __builtin_amdgcn_mfma_f32_16x16x32_f16(fi[2][kt], be[kt], an, 0, 0, 0);
            }
            const int R = row0 + rt * 16 + n16;
            v8h rz;
#pragma unroll
            for (int r = 0; r < 4; ++r) {
                rz[r]     = (_Float16)(ar[r] + bir[r]);
                rz[4 + r] = (_Float16)(az[r] + biz[r]);
            }
            *(v8h*)&gRZ[(size_t)R * 256 + cg * 32 + quad * 8] = rz;
            v4h nn;
#pragma unroll
            for (int r = 0; r < 4; ++r) nn[r] = (_Float16)(an[r] + bin_[r]);
            *(v4h*)&gN[(size_t)R * 128 + cg * 16 + quad * 4] = nn;
        }
        // stage next iter's obs (obs_lds reads all ended before the mid BAR)
#pragma unroll
        for (int q = 0; q < 4; ++q) {
            v4h pa = { (_Float16)nv[q].x, (_Float16)nv[q].y, (_Float16)nv[q].z, (_Float16)nv[q].w };
            *(v4h*)&obs_lds[srow * LDSS + sk + q * 4] = pa;
        }
        BAR();
    }
}

// ---------------------------------------------------------------------------
// K2: GRU recurrence. 32 blocks x 16 batch rows, 8 waves. Same math as r5
// (fused rational gates, 3 exp2 + 2 rcp), but all per-step addressing is
// RUNNING POINTERS (no 64-bit muls in the loop).
// ---------------------------------------------------------------------------
__global__ __launch_bounds__(512) void k2_recurrence(
    const float* __restrict__ hidden,
    const unsigned char* __restrict__ dones_raw,
    const _Float16* __restrict__ gRZ,
    _Float16* __restrict__ gN,
    const float* __restrict__ Wh,
    const float* __restrict__ bhn,
    float* __restrict__ out)
{
    __shared__ __align__(16) _Float16 h_lds[2][16 * LDSS];
    __shared__ __align__(16) unsigned char d_lds[(T_DIM + 1) * 16];
    __shared__ int byte_mode;
    const int tid  = threadIdx.x;
    const int w    = tid >> 6;
    const int lane = tid & 63;
    const int n16  = lane & 15;   // batch within group
    const int quad = lane >> 4;
    const int c16  = w * 16 + quad * 4;
    const int B0   = blockIdx.x * 16;

    if (tid == 0) byte_mode = 0;
    __syncthreads();
    {   // detect dones element width: byte==1 at non-4-aligned offset => 1-byte bools
        int hit = 0;
        for (int i = tid; i < 4096; i += 512)
            if ((i & 3) != 0 && dones_raw[i] == 1) hit = 1;
        if (hit) byte_mode = 1;
    }
    __syncthreads();
    const bool bm = (byte_mode != 0);

    // stage this block's dones slice: d_lds[t*16 + b]; row T zeroed
    {
        if (bm) {
            const int4 v = *(const int4*)(dones_raw + (size_t)tid * B_DIM + B0);
            *(int4*)&d_lds[tid * 16] = v;
        } else {
            const int* di = (const int*)dones_raw;
            const int* pp = di + (size_t)tid * B_DIM + B0;
            int4 wv; unsigned char* wb = (unsigned char*)&wv;
#pragma unroll
            for (int j = 0; j < 16; ++j) wb[j] = (unsigned char)(pp[j] != 0);
            *(int4*)&d_lds[tid * 16] = wv;
        }
        if (tid == 0) { int4 z = {0,0,0,0}; *(int4*)&d_lds[T_DIM * 16] = z; }
    }

    // Wh^T A-frags, gate scales folded in
    v8h fh[3][4];
#pragma unroll
    for (int g = 0; g < 3; ++g) {
        const float sc = (g == 2) ? SC_N : SC_R;
#pragma unroll
        for (int kt = 0; kt < 4; ++kt)
#pragma unroll
            for (int j = 0; j < 8; ++j) {
                const int k = kt * 32 + quad * 8 + j;
                fh[g][kt][j] = (_Float16)(Wh[k * G3 + g * H_DIM + w * 16 + n16] * sc);
            }
    }
    float bhnr[4];
#pragma unroll
    for (int r = 0; r < 4; ++r) bhnr[r] = bhn[c16 + r] * SC_N;

    __syncthreads();   // d_lds visible

    // init carry, pre-masked with done[0]
    const bool d0 = d_lds[n16] != 0;
    float hu[4];
#pragma unroll
    for (int r = 0; r < 4; ++r) {
        const float hv = hidden[(size_t)(B0 + n16) * H_DIM + c16 + r];
        hu[r] = d0 ? 0.f : hv;
    }
    {
        v4h hw = { (_Float16)hu[0], (_Float16)hu[1], (_Float16)hu[2], (_Float16)hu[3] };
        *(v4h*)&h_lds[0][n16 * LDSS + c16] = hw;
    }

    const size_t RZT = (size_t)B_DIM * 256;
    const size_t NT  = (size_t)B_DIM * 128;
    const _Float16* rzp = gRZ + (size_t)(B0 + n16) * 256 + w * 32 + quad * 8;
    _Float16*       np  = gN  + (size_t)(B0 + n16) * 128 + c16;

    // preload t=0,1; running prefetch pointers at t=2
    v8h s8_0 = *(const v8h*)(rzp);
    v4h s4_0 = *(const v4h*)(np);
    v8h s8_1 = *(const v8h*)(rzp + RZT);
    v4h s4_1 = *(const v4h*)(np + NT);
    const _Float16* pf8 = rzp + 2 * RZT;
    const _Float16* pf4 = np + 2 * NT;
    _Float16* yp = np;                 // ys store pointer (row t)
    const unsigned char* dp = &d_lds[16 + n16];   // done[t+1]
    __syncthreads();   // h_lds[0] visible

    auto STEP = [&](int t, v8h& s8, v4h& s4, const _Float16* hin, _Float16* hout)
        __attribute__((always_inline)) -> void {
        // prefetch t+2 from running pointers (stays in flight across BAR)
        const v8h gC8 = *(const v8h*)pf8;
        const v4h gC4 = *(const v4h*)pf4;
        const unsigned char dnx = *dp;

        v8h bh[4];
#pragma unroll
        for (int kt = 0; kt < 4; ++kt)
            bh[kt] = *(const v8h*)&hin[n16 * LDSS + kt * 32 + quad * 8];

        v4f ga0 = {0.f,0.f,0.f,0.f}, ga1 = {0.f,0.f,0.f,0.f}, ga2 = {0.f,0.f,0.f,0.f};
#pragma unroll
        for (int kt = 0; kt < 4; ++kt) {
            ga0 = __builtin_amdgcn_mfma_f32_16x16x32_f16(fh[0][kt], bh[kt], ga0, 0, 0, 0);
            ga1 = __builtin_amdgcn_mfma_f32_16x16x32_f16(fh[1][kt], bh[kt], ga1, 0, 0, 0);
            ga2 = __builtin_amdgcn_mfma_f32_16x16x32_f16(fh[2][kt], bh[kt], ga2, 0, 0, 0);
        }

        // fused gates: h = [ez*(en-1) + hu*(en+1)] / [(en+1)*(1+ez)]
        float hn[4];
#pragma unroll
        for (int r = 0; r < 4; ++r) {
            const float er = EXP2F((float)s8[r] + ga0[r]);
            const float rg = RCPF(1.f + er);
            const float sn = fmaf(rg, ga2[r] + bhnr[r], (float)s4[r]);
            const float en = EXP2F(sn);
            const float ez = EXP2F((float)s8[4 + r] + ga1[r]);
            const float enp = en + 1.f;
            const float num = fmaf(hu[r], enp, (en - 1.f) * ez);
            const float den = enp * (1.f + ez);
            hn[r] = num * RCPF(den);
        }

        // ys[t] (unmasked) -> gN row t (already consumed)
        v4h yv = { (_Float16)hn[0], (_Float16)hn[1], (_Float16)hn[2], (_Float16)hn[3] };
        *(v4h*)yp = yv;

        // mask with done[t+1] at write
        const bool dn = dnx != 0;
        v4h hz = { (_Float16)0.f, (_Float16)0.f, (_Float16)0.f, (_Float16)0.f };
        v4h hv = dn ? hz : yv;
#pragma unroll
        for (int r = 0; r < 4; ++r) hu[r] = dn ? 0.f : hn[r];
        *(v4h*)&hout[n16 * LDSS + c16] = hv;

        s8 = gC8; s4 = gC4;
        // advance running pointers; stop pf at row 511 (uniform scalar select)
        const size_t adv = (t < 509) ? 1 : 0;
        pf8 += adv * RZT; pf4 += adv * NT;
        yp += NT; dp += 16;
        BAR();
    };

    for (int t = 0; t < T_DIM; t += 2) {
        STEP(t,     s8_0, s4_0, h_lds[0], h_lds[1]);
        STEP(t + 1, s8_1, s4_1, h_lds[1], h_lds[0]);
    }

    // h_final (hu after t=511 is unmasked: d_lds row 512 zeroed)
#pragma unroll
    for (int r = 0; r < 4; ++r)
        out[(size_t)(B0 + n16) * H_DIM + c16 + r] = hu[r];
}

// ---------------------------------------------------------------------------
// K3: q = ys @ W_out + b_out over all T*B rows. ys = gN (f16).
// 4096 blocks x 256 thr (4 waves x 16 rows).
// ---------------------------------------------------------------------------
__global__ __launch_bounds__(256) void k3_qout(
    const _Float16* __restrict__ ys,
    const float* __restrict__ W_out,
    const float* __restrict__ b_out,
    float* __restrict__ qout)
{
    const int tid  = threadIdx.x;
    const int wv   = tid >> 6;
    const int lane = tid & 63;
    const int n16  = lane & 15;
    const int quad = lane >> 4;
    const int R0   = blockIdx.x * 64 + wv * 16;

    v8h fo[2][4];
#pragma unroll
    for (int ct = 0; ct < 2; ++ct)
#pragma unroll
        for (int kt = 0; kt < 4; ++kt)
#pragma unroll
            for (int j = 0; j < 8; ++j) {
                const int k = kt * 32 + quad * 8 + j;
                const int col = ct * 16 + n16;
                fo[ct][kt][j] = (col < A_DIM) ? (_Float16)W_out[k * A_DIM + col] : (_Float16)0.f;
            }
    float bq0[4], bq1[4];
#pragma unroll
    for (int r = 0; r < 4; ++r) {
        const int c0 = quad * 4 + r;
        const int c1 = 16 + quad * 4 + r;
        bq0[r] = b_out[c0];
        bq1[r] = (c1 < A_DIM) ? b_out[c1] : 0.f;
    }

    v8h by[4];
#pragma unroll
    for (int kt = 0; kt < 4; ++kt)
        by[kt] = *(const v8h*)(ys + (size_t)(R0 + n16) * 128 + kt * 32 + quad * 8);
    v4f q0 = {0.f,0.f,0.f,0.f}, q1 = {0.f,0.f,0.f,0.f};
#pragma unroll
    for (int kt = 0; kt < 4; ++kt) {
        q0 = __builtin_amdgcn_mfma_f32_16x16x32_f16(fo[0][kt], by[kt], q0, 0, 0, 0);
        q1 = __builtin_amdgcn_mfma_f32_16x16x32_f16(fo[1][kt], by[kt], q1, 0, 0, 0);
    }
    float* qp = qout + (size_t)(R0 + n16) * A_DIM;
#pragma unroll
    for (int r = 0; r < 4; ++r) qp[quad * 4 + r] = q0[r] + bq0[r];
    if (quad == 0) {
#pragma unroll
        for (int r = 0; r < 2; ++r) qp[16 + r] = q1[r] + bq1[r];
    }
}

extern "C" void kernel_launch(void* const* d_in, const int* in_sizes, int n_in,
                              void* d_out, int out_size, void* d_ws, size_t ws_size,
                              hipStream_t stream) {
    const float* hidden = (const float*)d_in[0];
    const float* obs    = (const float*)d_in[1];
    const unsigned char* dones = (const unsigned char*)d_in[2];
    const float* W_emb  = (const float*)d_in[3];
    const float* b_emb  = (const float*)d_in[4];
    const float* Wi     = (const float*)d_in[5];
    const float* bi     = (const float*)d_in[6];
    const float* Wh     = (const float*)d_in[7];
    const float* bhn    = (const float*)d_in[8];
    const float* W_out  = (const float*)d_in[9];
    const float* b_out  = (const float*)d_in[10];
    float* out = (float*)d_out;

    _Float16* gRZ = (_Float16*)d_ws;                              // [T*B][256] f16 = 128 MiB
    _Float16* gN  = gRZ + (size_t)T_DIM * B_DIM * 256;            // [T*B][128] f16 =  64 MiB

    hipLaunchKernelGGL(k1_embed_gi, dim3(256), dim3(512), 0, stream,
                       obs, W_emb, b_emb, Wi, bi, gRZ, gN);
    hipLaunchKernelGGL(k2_recurrence, dim3(32), dim3(512), 0, stream,
                       hidden, dones, gRZ, gN, Wh, bhn, out);
    hipLaunchKernelGGL(k3_qout, dim3(4096), dim3(256), 0, stream,
                       gN, W_out, b_out, out + (size_t)B_DIM * H_DIM);
}